// Round 1
// baseline (249.994 us; speedup 1.0000x reference)
//
#include <hip/hip_runtime.h>

// APMLSparse: B=4, N=M=4096, D=3.
// loss = sum over rows of sum_{kept j} p_ij * d_ij, where p = softmax_j(-d_i),
// kept = descending-p prefix until cumulative mass reaches P_MIN=0.8.
// Selection implemented as binary search on float bit pattern of d for the
// crossing value d* (ascending-d order == descending-p order).

#define NTHREADS 256
#define KPT 16            // 4096 / 256 elements per thread
#define NROWS_N 4096      // N
#define MCOLS 4096        // M

__device__ __forceinline__ float waveReduceSum(float v) {
    #pragma unroll
    for (int off = 32; off > 0; off >>= 1) v += __shfl_xor(v, off, 64);
    return v;
}
__device__ __forceinline__ float waveReduceMin(float v) {
    #pragma unroll
    for (int off = 32; off > 0; off >>= 1) v = fminf(v, __shfl_xor(v, off, 64));
    return v;
}
__device__ __forceinline__ float waveReduceMax(float v) {
    #pragma unroll
    for (int off = 32; off > 0; off >>= 1) v = fmaxf(v, __shfl_xor(v, off, 64));
    return v;
}

// Block-wide sum over 4 waves. Two barriers; result returned to all threads.
__device__ __forceinline__ float blockReduceSum(float v, float* sred, int tid) {
    v = waveReduceSum(v);
    if ((tid & 63) == 0) sred[tid >> 6] = v;
    __syncthreads();
    float r = sred[0] + sred[1] + sred[2] + sred[3];
    __syncthreads();
    return r;
}
__device__ __forceinline__ float blockReduceMin(float v, float* sred, int tid) {
    v = waveReduceMin(v);
    if ((tid & 63) == 0) sred[tid >> 6] = v;
    __syncthreads();
    float r = fminf(fminf(sred[0], sred[1]), fminf(sred[2], sred[3]));
    __syncthreads();
    return r;
}
__device__ __forceinline__ float blockReduceMax(float v, float* sred, int tid) {
    v = waveReduceMax(v);
    if ((tid & 63) == 0) sred[tid >> 6] = v;
    __syncthreads();
    float r = fmaxf(fmaxf(sred[0], sred[1]), fmaxf(sred[2], sred[3]));
    __syncthreads();
    return r;
}

__global__ __launch_bounds__(NTHREADS) void apml_row_kernel(
        const float* __restrict__ x, const float* __restrict__ y,
        float* __restrict__ partial) {
    __shared__ float sred[4];

    const int row = blockIdx.x;          // b*N + i
    const int b   = row >> 12;           // / 4096
    const int tid = threadIdx.x;

    const float x0 = x[row * 3 + 0];
    const float x1 = x[row * 3 + 1];
    const float x2 = x[row * 3 + 2];

    const float* yb = y + (size_t)b * MCOLS * 3;

    float d[KPT], p[KPT];
    float dmin_l = 3.4e38f, dmax_l = 0.0f;
    #pragma unroll
    for (int k = 0; k < KPT; ++k) {
        const int j = k * NTHREADS + tid;
        const float y0 = yb[j * 3 + 0];
        const float y1 = yb[j * 3 + 1];
        const float y2 = yb[j * 3 + 2];
        const float dx = x0 - y0, dy = x1 - y1, dz = x2 - y2;
        float sq = dx * dx + dy * dy + dz * dz;
        sq = fmaxf(sq, 1e-12f);          // EPS^2 clamp (matches reference)
        const float dd = sqrtf(sq);
        d[k] = dd;
        dmin_l = fminf(dmin_l, dd);
        dmax_l = fmaxf(dmax_l, dd);
    }

    const float dmin = blockReduceMin(dmin_l, sred, tid);
    const float dmax = blockReduceMax(dmax_l, sred, tid);

    // stable softmax over -d : p = exp(dmin - d) / Z
    float zl = 0.0f;
    #pragma unroll
    for (int k = 0; k < KPT; ++k) {
        const float w = __expf(dmin - d[k]);
        p[k] = w;
        zl += w;
    }
    const float Z = blockReduceSum(zl, sred, tid);
    const float invZ = 1.0f / Z;
    #pragma unroll
    for (int k = 0; k < KPT; ++k) p[k] *= invZ;

    // Binary search (on positive-float bit pattern) for minimal data value d*
    // with mass{d <= d*} >= P_MIN. Invariant: M(lo) < 0.8 <= M(hi).
    unsigned lo = __float_as_uint(dmin) - 1u;
    unsigned hi = __float_as_uint(dmax);
    while (hi - lo > 1u) {
        const unsigned mid = lo + ((hi - lo) >> 1);
        const float midf = __uint_as_float(mid);
        float ml = 0.0f;
        #pragma unroll
        for (int k = 0; k < KPT; ++k) ml += (d[k] <= midf) ? p[k] : 0.0f;
        const float mass = blockReduceSum(ml, sred, tid);
        if (mass >= 0.8f) hi = mid; else lo = mid;
    }
    const float dstar = __uint_as_float(hi);

    // Final pass: strict-below sums + tie stats at d == d*
    float mb = 0.0f, spd = 0.0f, cnt = 0.0f, spt = 0.0f;
    #pragma unroll
    for (int k = 0; k < KPT; ++k) {
        const bool below = (d[k] < dstar);
        const bool eq    = (d[k] == dstar);
        mb  += below ? p[k] : 0.0f;
        spd += below ? p[k] * d[k] : 0.0f;
        cnt += eq ? 1.0f : 0.0f;
        spt += eq ? p[k] : 0.0f;
    }
    mb  = blockReduceSum(mb,  sred, tid);
    spd = blockReduceSum(spd, sred, tid);
    cnt = blockReduceSum(cnt, sred, tid);
    spt = blockReduceSum(spt, sred, tid);

    if (tid == 0) {
        const float pt = spt / cnt;               // cnt >= 1 by construction
        const float R  = (0.8f - mb) / pt;        // > 0 since mb < 0.8
        int q = (int)ceilf(R);
        if (q < 1) q = 1;
        const int mt = (int)(cnt + 0.5f);
        if (q > mt) q = mt;
        partial[row] = spd + (float)q * pt * dstar;
    }
}

__global__ __launch_bounds__(NTHREADS) void apml_reduce_kernel(
        const float* __restrict__ part, float* __restrict__ out, int n) {
    __shared__ float sred[4];
    float s = 0.0f;
    for (int i = threadIdx.x; i < n; i += NTHREADS) s += part[i];
    s = waveReduceSum(s);
    if ((threadIdx.x & 63) == 0) sred[threadIdx.x >> 6] = s;
    __syncthreads();
    if (threadIdx.x == 0) out[0] = sred[0] + sred[1] + sred[2] + sred[3];
}

extern "C" void kernel_launch(void* const* d_in, const int* in_sizes, int n_in,
                              void* d_out, int out_size, void* d_ws, size_t ws_size,
                              hipStream_t stream) {
    const float* x = (const float*)d_in[0];   // [B, N, 3]
    const float* y = (const float*)d_in[1];   // [B, M, 3]
    float* out = (float*)d_out;               // scalar
    float* partial = (float*)d_ws;            // B*N floats

    const int B = in_sizes[0] / (NROWS_N * 3);
    const int nrows = B * NROWS_N;

    apml_row_kernel<<<nrows, NTHREADS, 0, stream>>>(x, y, partial);
    apml_reduce_kernel<<<1, NTHREADS, 0, stream>>>(partial, out, nrows);
}